// Round 8
// baseline (97.228 us; speedup 1.0000x reference)
//
#include <hip/hip_runtime.h>
#include <math.h>

#define W_ 4
#define S_ 32
#define H_ 32
#define KH_ 8
#define D_ 128
#define BS_ 16
#define M_ 64
#define NB_ 2048
#define G_ (H_ / KH_)        // 4 query heads per kv head
#define NG_ (S_ * KH_ * G_)  // 1024 output groups (== S*H)
#define SCALE_ 0.08838834764831845f

// R8: same phase-1 hot loop as R7 (95.4 us). Change: since the merge across
// ranks/splits is a PLAIN SUM (no online max since R4), partials are
// accumulated with device-scope atomicAdd directly into d_out (0.5 MB,
// L2/L3-resident -> no HBM partial round-trip, no 17MB phase-2 read).
// Pipeline: pa_zero (init accumulators; harness poisons d_out only once)
//           -> pa_phase1 (atomic accumulate) -> pa_norm (divide by sum(se)).
// Float-atomic ordering noise ~1e-6 << 4.88e-3 threshold; work per call is
// identical -> graph-capture safe.

__global__ __launch_bounds__(256) void pa_zero(float* __restrict__ out,
                                               float* __restrict__ se_acc) {
  const int i = blockIdx.x * 256 + threadIdx.x;
  if (i < NG_ * D_) out[i] = 0.f;
  if (i < NG_) se_acc[i] = 0.f;
}

template <int NSB>
__global__ __launch_bounds__(256) void pa_phase1(
    const float* __restrict__ q, const float* __restrict__ kc,
    const float* __restrict__ vc, const int* __restrict__ bt,
    const int* __restrict__ cl, float* __restrict__ out,
    float* __restrict__ se_acc) {
  const int wg = blockIdx.x;
  const int sb = wg % NSB;
  const int kh = (wg / NSB) % KH_;
  const int s = (wg / (NSB * KH_)) % S_;
  const int w = wg / (NSB * KH_ * S_);
  const int lane = threadIdx.x & 63;
  const int wv = threadIdx.x >> 6;  // page-interleave slot
  const int d_sub = lane >> 2;      // 0..15
  const int tc = lane & 3;          // lane owns tokens 4*tc..4*tc+3

  __shared__ float lds_o[4][G_][D_];  // 8 KB
  __shared__ float lds_se[4][G_];

  const int ctx = cl[w * S_ + s];
  const int nblk = (ctx + BS_ - 1) >> 4;
  const int pps = (nblk + NSB - 1) / NSB;
  const int j0 = sb * pps;
  const int j1 = min(j0 + pps, nblk);
  const int* bt_row = bt + (w * S_ + s) * M_;

  // Q fragments for all 4 heads of this kv-head (L2-hot, tiny)
  const float* qbase = q + ((size_t)s * H_ + kh * G_) * D_;
  float qreg[G_][8];
#pragma unroll
  for (int h = 0; h < G_; ++h)
#pragma unroll
    for (int i = 0; i < 8; ++i) qreg[h][i] = qbase[h * D_ + d_sub + 16 * i];

  float oacc[G_][8];  // per head: partial O[d_sub+16i] over lane's 4 tokens
  float se[G_];
#pragma unroll
  for (int h = 0; h < G_; ++h) {
    se[h] = 0.f;
#pragma unroll
    for (int i = 0; i < 8; ++i) oacc[h][i] = 0.f;
  }

  for (int j = j0 + wv; j < j1; j += 4) {
    const int page = bt_row[j];
    const size_t pbase = ((((size_t)w * NB_ + page) * KH_) + kh) * (size_t)(D_ * BS_);
    const float* Kc = kc + pbase;
    const float* Vc = vc + pbase;

    // issue the whole page's loads up front (8KB K + 8KB V per wave)
    float4 k4[8], v4[8];
#pragma unroll
    for (int i = 0; i < 8; ++i)
      k4[i] = *reinterpret_cast<const float4*>(Kc + (d_sub + 16 * i) * BS_ + 4 * tc);
#pragma unroll
    for (int i = 0; i < 8; ++i)
      v4[i] = *reinterpret_cast<const float4*>(Vc + (d_sub + 16 * i) * BS_ + 4 * tc);

    // ---- QK^T partials for 4 heads
    float4 a[G_];
#pragma unroll
    for (int h = 0; h < G_; ++h) a[h] = make_float4(0.f, 0.f, 0.f, 0.f);
#pragma unroll
    for (int i = 0; i < 8; ++i)
#pragma unroll
      for (int h = 0; h < G_; ++h) {
        a[h].x = fmaf(qreg[h][i], k4[i].x, a[h].x);
        a[h].y = fmaf(qreg[h][i], k4[i].y, a[h].y);
        a[h].z = fmaf(qreg[h][i], k4[i].z, a[h].z);
        a[h].w = fmaf(qreg[h][i], k4[i].w, a[h].w);
      }
    // allreduce over 16 d_sub classes; 16 independent chains interleave
#pragma unroll
    for (int off = 4; off <= 32; off <<= 1)
#pragma unroll
      for (int h = 0; h < G_; ++h) {
        a[h].x += __shfl_xor(a[h].x, off);
        a[h].y += __shfl_xor(a[h].y, off);
        a[h].z += __shfl_xor(a[h].z, off);
        a[h].w += __shfl_xor(a[h].w, off);
      }

    const int tbase = j * BS_ + 4 * tc;
    const bool in0 = tbase + 0 < ctx, in1 = tbase + 1 < ctx,
               in2 = tbase + 2 < ctx, in3 = tbase + 3 < ctx;

#pragma unroll
    for (int h = 0; h < G_; ++h) {
      const float p0 = in0 ? __expf(a[h].x * SCALE_) : 0.f;
      const float p1 = in1 ? __expf(a[h].y * SCALE_) : 0.f;
      const float p2 = in2 ? __expf(a[h].z * SCALE_) : 0.f;
      const float p3 = in3 ? __expf(a[h].w * SCALE_) : 0.f;
      se[h] += (p0 + p1) + (p2 + p3);
#pragma unroll
      for (int i = 0; i < 8; ++i) {
        oacc[h][i] = fmaf(p0, v4[i].x, oacc[h][i]);
        oacc[h][i] = fmaf(p1, v4[i].y, oacc[h][i]);
        oacc[h][i] = fmaf(p2, v4[i].z, oacc[h][i]);
        oacc[h][i] = fmaf(p3, v4[i].w, oacc[h][i]);
      }
    }
  }

  // ---- wave-level tc-allreduce (lane bits 0..1)
#pragma unroll
  for (int off = 1; off <= 2; off <<= 1)
#pragma unroll
    for (int h = 0; h < G_; ++h) {
#pragma unroll
      for (int i = 0; i < 8; ++i) oacc[h][i] += __shfl_xor(oacc[h][i], off);
      se[h] += __shfl_xor(se[h], off);
    }

  // ---- block-level reduce of the 4 wave-partials via LDS
  if (tc == 0) {
#pragma unroll
    for (int h = 0; h < G_; ++h) {
#pragma unroll
      for (int i = 0; i < 8; ++i) lds_o[wv][h][16 * i + d_sub] = oacc[h][i];
      if (d_sub == 0) lds_se[wv][h] = se[h];
    }
  }
  __syncthreads();

  // ---- device-scope atomic accumulate into d_out (L2/L3-resident, 0.5 MB)
#pragma unroll
  for (int e = 0; e < 2; ++e) {
    const int idx = threadIdx.x + 256 * e;  // 512 (h,d) pairs / 256 threads
    const int h = idx >> 7, d = idx & 127;
    const float v =
        (lds_o[0][h][d] + lds_o[1][h][d]) + (lds_o[2][h][d] + lds_o[3][h][d]);
    const int grp = (s * KH_ + kh) * G_ + h;  // == s*H + head
    atomicAdd(&out[(size_t)grp * D_ + d], v);
  }
  if (threadIdx.x < G_) {
    const int h = threadIdx.x;
    const int grp = (s * KH_ + kh) * G_ + h;
    atomicAdd(&se_acc[grp],
              (lds_se[0][h] + lds_se[1][h]) + (lds_se[2][h] + lds_se[3][h]));
  }
}

// Final: out[grp][d] /= sum(se) for the group (runs after phase-1 completes).
__global__ __launch_bounds__(128) void pa_norm(float* __restrict__ out,
                                               const float* __restrict__ se_acc) {
  const int grp = blockIdx.x;
  out[(size_t)grp * D_ + threadIdx.x] /= se_acc[grp];
}

extern "C" void kernel_launch(void* const* d_in, const int* in_sizes, int n_in,
                              void* d_out, int out_size, void* d_ws, size_t ws_size,
                              hipStream_t stream) {
  (void)in_sizes; (void)n_in; (void)out_size; (void)ws_size;
  const float* q = (const float*)d_in[0];
  const float* kc = (const float*)d_in[1];
  const float* vc = (const float*)d_in[2];
  const int* bt = (const int*)d_in[3];
  const int* cl = (const int*)d_in[4];
  float* out = (float*)d_out;
  float* se_acc = (float*)d_ws;  // NG_ floats (4 KB)

  pa_zero<<<dim3((NG_ * D_ + 255) / 256), dim3(256), 0, stream>>>(out, se_acc);
  pa_phase1<4><<<dim3(W_ * S_ * KH_ * 4), dim3(256), 0, stream>>>(
      q, kc, vc, bt, cl, out, se_acc);
  pa_norm<<<dim3(NG_), dim3(128), 0, stream>>>(out, se_acc);
}

// Round 9
// 89.921 us; speedup vs baseline: 1.0813x; 1.0813x over previous
//
#include <hip/hip_runtime.h>
#include <math.h>

#define W_ 4
#define S_ 32
#define H_ 32
#define KH_ 8
#define D_ 128
#define BS_ 16
#define M_ 64
#define NB_ 2048
#define G_ (H_ / KH_)        // 4 query heads per kv head
#define NG_ (S_ * KH_ * G_)  // 1024 output groups (== S*H)
#define SCALE_ 0.08838834764831845f

// R9 = R7 (95.4 us; best) with ONE knob changed: occupancy 2 -> 3 waves/SIMD.
//  (a) page body reordered so K-regs and V-regs are never simultaneously
//      live: K loads -> QK FMA -> V loads -> shuffle reduce -> exp + PV
//      (V latency hides under the 4-round DS reduce + exp);
//  (b) __launch_bounds__(256, 3) forces the allocator to <=~168 VGPR.
// R8's atomic epilogue reverted (partials are L3-resident; atomics gained
// nothing). Epilogue = R7's block-level LDS reduce, R = W*NSB = 16 partials.
template <int NSB>
__global__ __launch_bounds__(256, 3) void pa_phase1(
    const float* __restrict__ q, const float* __restrict__ kc,
    const float* __restrict__ vc, const int* __restrict__ bt,
    const int* __restrict__ cl, float* __restrict__ o_ws,
    float* __restrict__ se_ws) {
  const int wg = blockIdx.x;
  const int sb = wg % NSB;
  const int kh = (wg / NSB) % KH_;
  const int s = (wg / (NSB * KH_)) % S_;
  const int w = wg / (NSB * KH_ * S_);
  const int lane = threadIdx.x & 63;
  const int wv = threadIdx.x >> 6;  // page-interleave slot
  const int d_sub = lane >> 2;      // 0..15
  const int tc = lane & 3;          // lane owns tokens 4*tc..4*tc+3

  __shared__ float lds_o[4][G_][D_];  // 8 KB
  __shared__ float lds_se[4][G_];

  const int ctx = cl[w * S_ + s];
  const int nblk = (ctx + BS_ - 1) >> 4;
  const int pps = (nblk + NSB - 1) / NSB;
  const int j0 = sb * pps;
  const int j1 = min(j0 + pps, nblk);
  const int* bt_row = bt + (w * S_ + s) * M_;

  // Q fragments for all 4 heads of this kv-head (L2-hot, tiny)
  const float* qbase = q + ((size_t)s * H_ + kh * G_) * D_;
  float qreg[G_][8];
#pragma unroll
  for (int h = 0; h < G_; ++h)
#pragma unroll
    for (int i = 0; i < 8; ++i) qreg[h][i] = qbase[h * D_ + d_sub + 16 * i];

  float oacc[G_][8];  // per head: partial O[d_sub+16i] over lane's 4 tokens
  float se[G_];
#pragma unroll
  for (int h = 0; h < G_; ++h) {
    se[h] = 0.f;
#pragma unroll
    for (int i = 0; i < 8; ++i) oacc[h][i] = 0.f;
  }

  for (int j = j0 + wv; j < j1; j += 4) {
    const int page = bt_row[j];
    const size_t pbase = ((((size_t)w * NB_ + page) * KH_) + kh) * (size_t)(D_ * BS_);
    const float* Kc = kc + pbase;
    const float* Vc = vc + pbase;

    // ---- K loads (8 float4); consumed by QK FMA, then dead
    float4 k4[8];
#pragma unroll
    for (int i = 0; i < 8; ++i)
      k4[i] = *reinterpret_cast<const float4*>(Kc + (d_sub + 16 * i) * BS_ + 4 * tc);

    // ---- QK^T partials for 4 heads (waits on K)
    float4 a[G_];
#pragma unroll
    for (int h = 0; h < G_; ++h) a[h] = make_float4(0.f, 0.f, 0.f, 0.f);
#pragma unroll
    for (int i = 0; i < 8; ++i)
#pragma unroll
      for (int h = 0; h < G_; ++h) {
        a[h].x = fmaf(qreg[h][i], k4[i].x, a[h].x);
        a[h].y = fmaf(qreg[h][i], k4[i].y, a[h].y);
        a[h].z = fmaf(qreg[h][i], k4[i].z, a[h].z);
        a[h].w = fmaf(qreg[h][i], k4[i].w, a[h].w);
      }

    // ---- V loads issued now (independent); latency hides under DS reduce
    float4 v4[8];
#pragma unroll
    for (int i = 0; i < 8; ++i)
      v4[i] = *reinterpret_cast<const float4*>(Vc + (d_sub + 16 * i) * BS_ + 4 * tc);

    // ---- allreduce over 16 d_sub classes (lane bits 2..5)
#pragma unroll
    for (int off = 4; off <= 32; off <<= 1)
#pragma unroll
      for (int h = 0; h < G_; ++h) {
        a[h].x += __shfl_xor(a[h].x, off);
        a[h].y += __shfl_xor(a[h].y, off);
        a[h].z += __shfl_xor(a[h].z, off);
        a[h].w += __shfl_xor(a[h].w, off);
      }

    const int tbase = j * BS_ + 4 * tc;
    const bool in0 = tbase + 0 < ctx, in1 = tbase + 1 < ctx,
               in2 = tbase + 2 < ctx, in3 = tbase + 3 < ctx;

#pragma unroll
    for (int h = 0; h < G_; ++h) {
      const float p0 = in0 ? __expf(a[h].x * SCALE_) : 0.f;
      const float p1 = in1 ? __expf(a[h].y * SCALE_) : 0.f;
      const float p2 = in2 ? __expf(a[h].z * SCALE_) : 0.f;
      const float p3 = in3 ? __expf(a[h].w * SCALE_) : 0.f;
      se[h] += (p0 + p1) + (p2 + p3);
#pragma unroll
      for (int i = 0; i < 8; ++i) {
        oacc[h][i] = fmaf(p0, v4[i].x, oacc[h][i]);
        oacc[h][i] = fmaf(p1, v4[i].y, oacc[h][i]);
        oacc[h][i] = fmaf(p2, v4[i].z, oacc[h][i]);
        oacc[h][i] = fmaf(p3, v4[i].w, oacc[h][i]);
      }
    }
  }

  // ---- wave-level tc-allreduce (lane bits 0..1)
#pragma unroll
  for (int off = 1; off <= 2; off <<= 1)
#pragma unroll
    for (int h = 0; h < G_; ++h) {
#pragma unroll
      for (int i = 0; i < 8; ++i) oacc[h][i] += __shfl_xor(oacc[h][i], off);
      se[h] += __shfl_xor(se[h], off);
    }

  // ---- block-level reduce of the 4 wave-partials via LDS
  if (tc == 0) {
#pragma unroll
    for (int h = 0; h < G_; ++h) {
#pragma unroll
      for (int i = 0; i < 8; ++i) lds_o[wv][h][16 * i + d_sub] = oacc[h][i];
      if (d_sub == 0) lds_se[wv][h] = se[h];
    }
  }
  __syncthreads();

  const int r = w * NSB + sb;
#pragma unroll
  for (int e = 0; e < 2; ++e) {
    const int idx = threadIdx.x + 256 * e;  // 512 (h,d) pairs / 256 threads
    const int h = idx >> 7, d = idx & 127;
    const float v =
        (lds_o[0][h][d] + lds_o[1][h][d]) + (lds_o[2][h][d] + lds_o[3][h][d]);
    const int grp = (s * KH_ + kh) * G_ + h;  // == s*H + head
    o_ws[((size_t)r * NG_ + grp) * D_ + d] = v;
  }
  if (threadIdx.x < G_) {
    const int h = threadIdx.x;
    const int grp = (s * KH_ + kh) * G_ + h;
    se_ws[(size_t)r * NG_ + grp] =
        (lds_se[0][h] + lds_se[1][h]) + (lds_se[2][h] + lds_se[3][h]);
  }
}

// Phase 2: merge R partials per group: out = sum_r O_r / sum_r se_r
template <int R>
__global__ __launch_bounds__(128) void pa_reduce(
    const float* __restrict__ o_ws, const float* __restrict__ se_ws,
    float* __restrict__ out) {
  const int grp = blockIdx.x;  // s*H + h
  const int d = threadIdx.x;   // 0..127

  float denom = 0.f, acc = 0.f;
#pragma unroll
  for (int r = 0; r < R; ++r) {
    denom += se_ws[(size_t)r * NG_ + grp];
    acc += o_ws[((size_t)r * NG_ + grp) * D_ + d];
  }
  out[(size_t)grp * D_ + d] = acc / denom;
}

extern "C" void kernel_launch(void* const* d_in, const int* in_sizes, int n_in,
                              void* d_out, int out_size, void* d_ws, size_t ws_size,
                              hipStream_t stream) {
  (void)in_sizes; (void)n_in; (void)out_size;
  const float* q = (const float*)d_in[0];
  const float* kc = (const float*)d_in[1];
  const float* vc = (const float*)d_in[2];
  const int* bt = (const int*)d_in[3];
  const int* cl = (const int*)d_in[4];
  float* out = (float*)d_out;

  // R = W * NSB block-partials; pick largest NSB fitting the workspace
  int nsb = 4;
  while (nsb > 1 &&
         (size_t)(W_ * nsb) * NG_ * (D_ + 1) * sizeof(float) > ws_size)
    nsb >>= 1;

  const int R = W_ * nsb;
  float* o_ws = (float*)d_ws;                 // R*NG*D floats
  float* se_ws = o_ws + (size_t)R * NG_ * D_; // R*NG floats

  const dim3 blk1(256), blk2(128), grid2(NG_);
  switch (nsb) {
    case 4:
      pa_phase1<4><<<dim3(W_ * S_ * KH_ * 4), blk1, 0, stream>>>(q, kc, vc, bt, cl, o_ws, se_ws);
      pa_reduce<16><<<grid2, blk2, 0, stream>>>(o_ws, se_ws, out);
      break;
    case 2:
      pa_phase1<2><<<dim3(W_ * S_ * KH_ * 2), blk1, 0, stream>>>(q, kc, vc, bt, cl, o_ws, se_ws);
      pa_reduce<8><<<grid2, blk2, 0, stream>>>(o_ws, se_ws, out);
      break;
    default:
      pa_phase1<1><<<dim3(W_ * S_ * KH_), blk1, 0, stream>>>(q, kc, vc, bt, cl, o_ws, se_ws);
      pa_reduce<4><<<grid2, blk2, 0, stream>>>(o_ws, se_ws, out);
      break;
  }
}